// Round 8
// baseline (859.427 us; speedup 1.0000x reference)
//
#include <hip/hip_runtime.h>
#include <type_traits>

// LSTMNet: B=1024, T=2048, H=64, NC=10, input_size=1.
// R21: TWO independent 4-row batch groups per block, interleaved in one
// instruction stream, ONE barrier per step covering both groups' h-writes.
// 128 blocks x 8 rows. Per-group math/layout byte-identical to R20.
// Why: R20's step = ~617cy, of which MFMA pipe is only 155cy (8 x 19.4/SIMD);
// the rest is ds_read latency + serial update chain + barrier. Group B's 8
// MFMAs issue while group A's update chain (~70cy dependent VALU) and read
// latencies drain -> interval ~650cy serves TWO steps (~325cy/step).
// B-frags/bias/wih registers are SHARED between groups (same weights), so
// pipe cost per row halves vs co-resident blocks (the R15 failure mode).
// Source order: A-reads, B-reads, A-MFMAs, B-MFMAs, A-update, B-update ->
// A's update overlaps B's MFMA issue naturally.
// Precision: identical per-row math to R20 (absmax 9.77e-4 measured).

#define T_STEPS 2048
#define HID 64
#define NCLS 10
#define XCH 128   // x chunk length (steps)
#define ROWS 8    // batch rows per block (2 groups of 4)

#define KQS 40    // kq stride in shorts (80B = 20 banks, 16B-aligned)
#define KTS 168   // kt stride in shorts (4*KQS + 8 pad; 336B, 16B-aligned)

typedef short bf16x8 __attribute__((ext_vector_type(8)));
typedef float f32x4 __attribute__((ext_vector_type(4)));

__device__ __forceinline__ unsigned short f2bf(float f) {  // RNE f32->bf16
    unsigned u = __builtin_bit_cast(unsigned, f);
    u = u + 0x7FFFu + ((u >> 16) & 1u);
    return (unsigned short)(u >> 16);
}

__global__ __attribute__((amdgpu_flat_work_group_size(256, 256)))
void lstm_mfma_kernel(
    const float* __restrict__ x,      // [B, 1, T]
    const float* __restrict__ W_ih,   // [256, 1]
    const float* __restrict__ W_hh,   // [256, 64]
    const float* __restrict__ b_ih,   // [256]
    const float* __restrict__ b_hh,   // [256]
    const float* __restrict__ fc1_w,  // [64, 64]
    const float* __restrict__ fc1_b,  // [64]
    const float* __restrict__ fc2_w,  // [10, 64]
    const float* __restrict__ fc2_b,  // [10]
    float* __restrict__ out)          // [B, 10]
{
    const int tid  = threadIdx.x;
    const int lane = tid & 63;
    const int w    = tid >> 6;        // wave id = unit-chunk owner
    const int quad = lane >> 4;       // batch row within group (D-row 4*quad)
    const int col  = lane & 15;
    const int row0 = blockIdx.x * ROWS;

    const float L2E = 1.4426950408889634f;

    // ---- LDS union: 32KB staging (dead after B-frag load) overlaps runtime ----
    __shared__ __align__(16) char smem[32768];
    short* whi = (short*)smem;                 // staging [0,32768)
    // runtime (valid only after the staging->register handoff sync):
    short (*abufA)[2 * KTS]    = (short(*)[2 * KTS])smem;            // 1344 B
    short (*abufB)[2 * KTS]    = (short(*)[2 * KTS])(smem + 1344);   // 1344 B
    float (*xlds)[XCH + 4]     = (float(*)[XCH + 4])(smem + 2688);   // 4224 B
    float (*hf)[HID + 1]       = (float(*)[HID + 1])(smem + 6912);   // 2080 B
    float (*r1buf)[HID + 1]    = (float(*)[HID + 1])(smem + 8992);   // 2080 B

    // ---- stage: W_hh f32 -> bf16 fragments, pre-scaled per gate ----
    // tile t_ = g*4 + u4  => wave w (reading t_ = gg*4 + w) gets all 4 gates
    // for units 16w..16w+15.
    for (int idx = tid; idx < 256 * 64; idx += 256) {
        int r_ = idx >> 6;            // gate-major row 0..255
        int k  = idx & 63;
        int g = r_ >> 6, u = r_ & 63;
        float scg = (g == 2) ? -2.0f * L2E : -L2E;
        float f = W_hh[r_ * 64 + k] * scg;
        int u4 = u >> 4, n = u & 15;
        int kt = k >> 5, kq = (k & 31) >> 3, j = k & 7;
        int off = (((g * 4 + u4) * 2 + kt) * 64 + (kq * 16 + n)) * 8 + j;
        whi[off] = (short)f2bf(f);
    }
    __syncthreads();

    // ---- B fragments -> registers (wave w: tiles t_ = gg*4 + w) ----
    // SHARED between both batch groups (same weights).
    const int u0 = w * 16 + col;      // this lane's unit (cols of all 4 tiles)
    bf16x8 Bq[4][2];
    f32x4 biasC[4];
    f32x4 zerov = {0.f, 0.f, 0.f, 0.f};
    #pragma unroll
    for (int gg = 0; gg < 4; ++gg) {
        int t_ = gg * 4 + w;
        #pragma unroll
        for (int kt = 0; kt < 2; ++kt) {
            int off = ((t_ * 2 + kt) * 64 + lane) * 8;
            Bq[gg][kt] = *(const bf16x8*)&whi[off];
            asm volatile("" : "+v"(Bq[gg][kt]));
        }
        float scg = (gg == 2) ? -2.0f * L2E : -L2E;
        float bs = (b_ih[gg * HID + u0] + b_hh[gg * HID + u0]) * scg;
        #pragma unroll
        for (int r = 0; r < 4; ++r) biasC[gg][r] = bs;
    }
    __syncthreads();   // all waves done READING staging; smem may be reused now

    // zero ALL A buffers (h0 = 0): 2 groups x 2 bufs x 336 shorts
    for (int idx = tid; idx < 2 * 2 * 2 * KTS; idx += 256) ((short*)smem)[idx] = 0;

    // ---- update constants: quad q owns cells (rows q and q+4, unit u0) ----
    float wih_u[4];
    #pragma unroll
    for (int gg = 0; gg < 4; ++gg) {
        float scg = (gg == 2) ? -2.0f * L2E : -L2E;
        wih_u[gg] = W_ih[gg * HID + u0] * scg;
    }
    float ccA = 0.f, hlA = 0.f;      // group A: batch row quad
    float ccB = 0.f, hlB = 0.f;      // group B: batch row quad+4

    // invariant LDS coords (compact layout; same for both groups)
    const int ard0 = (lane >> 4) * KQS + ((lane >> 2) & 3) * 8;   // kt1 at +KTS
    const int awr  = (u0 >> 5) * KTS + ((u0 >> 3) & 3) * KQS + quad * 8 + (u0 & 7);

    const float* xbase = x + (size_t)row0 * T_STEPS;
    __syncthreads();   // abufs zeroed

    auto step = [&](auto cur_c, int tl) __attribute__((always_inline)) {
        constexpr int CUR = decltype(cur_c)::value;
        constexpr int NXT = CUR ^ 1;

        // issue all LDS reads up front (latencies overlap)
        bf16x8 A0a = *(const bf16x8*)&abufA[CUR][ard0];
        bf16x8 A1a = *(const bf16x8*)&abufA[CUR][ard0 + KTS];
        bf16x8 A0b = *(const bf16x8*)&abufB[CUR][ard0];
        bf16x8 A1b = *(const bf16x8*)&abufB[CUR][ard0 + KTS];
        float xvA = xlds[quad][tl];
        float xvB = xlds[quad + 4][tl];

        // ---- group A MFMAs first (R16-best order: all lo, then all hi) ----
        f32x4 aloA[4], ahiA[4], aloB[4], ahiB[4];
        #pragma unroll
        for (int gg = 0; gg < 4; ++gg)
            aloA[gg] = __builtin_amdgcn_mfma_f32_16x16x32_bf16(A0a, Bq[gg][0], biasC[gg], 0, 0, 0);
        #pragma unroll
        for (int gg = 0; gg < 4; ++gg)
            ahiA[gg] = __builtin_amdgcn_mfma_f32_16x16x32_bf16(A1a, Bq[gg][1], zerov, 0, 0, 0);
        // ---- group B MFMAs (issue while A's update chain runs) ----
        #pragma unroll
        for (int gg = 0; gg < 4; ++gg)
            aloB[gg] = __builtin_amdgcn_mfma_f32_16x16x32_bf16(A0b, Bq[gg][0], biasC[gg], 0, 0, 0);
        #pragma unroll
        for (int gg = 0; gg < 4; ++gg)
            ahiB[gg] = __builtin_amdgcn_mfma_f32_16x16x32_bf16(A1b, Bq[gg][1], zerov, 0, 0, 0);

        // ---- group A update: quad q -> D-row 4q (reg0), all 64 lanes ----
        {
            float a0 = fmaf(xvA, wih_u[0], aloA[0][0] + ahiA[0][0]);
            float a1 = fmaf(xvA, wih_u[1], aloA[1][0] + ahiA[1][0]);
            float a2 = fmaf(xvA, wih_u[2], aloA[2][0] + ahiA[2][0]);
            float a3 = fmaf(xvA, wih_u[3], aloA[3][0] + ahiA[3][0]);
            float ig = __builtin_amdgcn_rcpf(1.0f + __builtin_amdgcn_exp2f(a0));
            float fg = __builtin_amdgcn_rcpf(1.0f + __builtin_amdgcn_exp2f(a1));
            float gv = fmaf(2.0f, __builtin_amdgcn_rcpf(1.0f + __builtin_amdgcn_exp2f(a2)), -1.0f);
            float og = __builtin_amdgcn_rcpf(1.0f + __builtin_amdgcn_exp2f(a3));
            ccA = fmaf(fg, ccA, ig * gv);
            float ec = __builtin_amdgcn_exp2f(-2.8853900817779268f * ccA);
            float th = fmaf(2.0f, __builtin_amdgcn_rcpf(1.0f + ec), -1.0f);
            hlA = og * th;
            unsigned hp;
            asm("v_cvt_pk_bf16_f32 %0, %1, %2" : "=v"(hp) : "v"(hlA), "v"(hlA));
            abufA[NXT][awr] = (short)hp;
        }
        // ---- group B update ----
        {
            float a0 = fmaf(xvB, wih_u[0], aloB[0][0] + ahiB[0][0]);
            float a1 = fmaf(xvB, wih_u[1], aloB[1][0] + ahiB[1][0]);
            float a2 = fmaf(xvB, wih_u[2], aloB[2][0] + ahiB[2][0]);
            float a3 = fmaf(xvB, wih_u[3], aloB[3][0] + ahiB[3][0]);
            float ig = __builtin_amdgcn_rcpf(1.0f + __builtin_amdgcn_exp2f(a0));
            float fg = __builtin_amdgcn_rcpf(1.0f + __builtin_amdgcn_exp2f(a1));
            float gv = fmaf(2.0f, __builtin_amdgcn_rcpf(1.0f + __builtin_amdgcn_exp2f(a2)), -1.0f);
            float og = __builtin_amdgcn_rcpf(1.0f + __builtin_amdgcn_exp2f(a3));
            ccB = fmaf(fg, ccB, ig * gv);
            float ec = __builtin_amdgcn_exp2f(-2.8853900817779268f * ccB);
            float th = fmaf(2.0f, __builtin_amdgcn_rcpf(1.0f + ec), -1.0f);
            hlB = og * th;
            unsigned hp;
            asm("v_cvt_pk_bf16_f32 %0, %1, %2" : "=v"(hp) : "v"(hlB), "v"(hlB));
            abufB[NXT][awr] = (short)hp;
        }
        __syncthreads();   // both groups' h-frags visible (ONE barrier/step)
    };

    #pragma unroll 1
    for (int tc = 0; tc < T_STEPS; tc += 2) {
        const int tl = tc & (XCH - 1);
        if (tl == 0) {
            // refill x chunk: wave w writes rows w and w+4 (consecutive dwords)
            {
                int i = lane;
                const float* srcA = xbase + (size_t)w * T_STEPS + tc;
                const float* srcB = xbase + (size_t)(w + 4) * T_STEPS + tc;
                xlds[w][i]          = srcA[i];
                xlds[w][i + 64]     = srcA[i + 64];
                xlds[w + 4][i]      = srcB[i];
                xlds[w + 4][i + 64] = srcB[i + 64];
            }
            __syncthreads();
        }
        step(std::integral_constant<int, 0>{}, tl);      // reads buf0, writes buf1
        step(std::integral_constant<int, 1>{}, tl + 1);  // reads buf1, writes buf0
    }

    // ---- epilogue: gather h, fc1 (relu) + fc2 ----
    hf[quad][u0]     = hlA;   // group A: rows 0..3
    hf[quad + 4][u0] = hlB;   // group B: rows 4..7
    __syncthreads();

    // fc1: 8 rows x 64 units = 512 dots; each thread does rows w and w+4
    {
        #pragma unroll
        for (int grp = 0; grp < 2; ++grp) {
            int m = w + grp * 4;
            float s = fc1_b[lane];
            const float4* wrow = (const float4*)(fc1_w + lane * HID);
            #pragma unroll
            for (int j4 = 0; j4 < HID / 4; ++j4) {
                float4 wv = wrow[j4];
                s = fmaf(hf[m][j4 * 4 + 0], wv.x, s);
                s = fmaf(hf[m][j4 * 4 + 1], wv.y, s);
                s = fmaf(hf[m][j4 * 4 + 2], wv.z, s);
                s = fmaf(hf[m][j4 * 4 + 3], wv.w, s);
            }
            r1buf[m][lane] = fmaxf(s, 0.0f);
        }
    }
    __syncthreads();

    if (tid < ROWS * NCLS) {
        int m = tid / NCLS, cls = tid % NCLS;
        float s = fc2_b[cls];
        const float* w2 = fc2_w + cls * HID;
        #pragma unroll
        for (int j = 0; j < HID; ++j) s = fmaf(r1buf[m][j], w2[j], s);
        out[(size_t)(row0 + m) * NCLS + cls] = s;
    }
}

extern "C" void kernel_launch(void* const* d_in, const int* in_sizes, int n_in,
                              void* d_out, int out_size, void* d_ws, size_t ws_size,
                              hipStream_t stream) {
    const float* x     = (const float*)d_in[0];
    const float* W_ih  = (const float*)d_in[1];
    const float* W_hh  = (const float*)d_in[2];
    const float* b_ih  = (const float*)d_in[3];
    const float* b_hh  = (const float*)d_in[4];
    const float* fc1_w = (const float*)d_in[5];
    const float* fc1_b = (const float*)d_in[6];
    const float* fc2_w = (const float*)d_in[7];
    const float* fc2_b = (const float*)d_in[8];
    float* out = (float*)d_out;

    dim3 grid(128);   // 1024 rows / 8 rows per block
    dim3 block(256);  // 4 waves (1 per SIMD)
    lstm_mfma_kernel<<<grid, block, 0, stream>>>(x, W_ih, W_hh, b_ih, b_hh,
                                                 fc1_w, fc1_b, fc2_w, fc2_b, out);
}

// Round 10
// 541.517 us; speedup vs baseline: 1.5871x; 1.5871x over previous
//
#include <hip/hip_runtime.h>
#include <type_traits>

// LSTMNet: B=1024, T=2048, H=64, NC=10, input_size=1.
// R22 (resubmit; prior attempt hit container-infra failure, no signal):
// R20 (best measured, 527us rocprof) + safe micro bundle:
//  (a) amdgpu_waves_per_eu(1,1): truthful (1 block/CU, 4 waves on 4 SIMDs
//      -> exactly 1 wave/EU); frees regalloc/scheduler.
//  (b) x-chunk prefetch: global_load next chunk's x into regs right after
//      the boundary barrier, consumed 128 steps later -> removes ~900cy
//      exposed HBM latency per boundary (16 boundaries).
//  (c) xv LDS reads for both steps hoisted to iteration top (pre-MFMA
//      lgkm wait covers only A-frag reads).
// L model (calibrated R13/R14/R15/R16/R21): 617cy = ~296 MFMA (8 x ~37cy
// solo-wave issue) + ~130 ds_read + ~100 update chain + ~90 write/barrier.
// MFMA segment irreducible at bf16 (8/wave forced: 256 gate-units / 4
// waves / K=32 split; i8 K=64 would halve it but expected absmax 3-6e-3
// exceeds budget). R21 lesson: total time = 2048 x L, block count is
// irrelevant -> minimize L only.
// Structure: 256 blocks x 4 waves, ROWS=4 (quad q = batch row q -> D-row
// 4q reg0), fused gate+update, 1 barrier + 1 LDS round trip per step,
// compact 4-row A-exchange layout (conflicts 1.72e7 -> 3.95e5 verified).
// Precision: bit-identical math to R20 (absmax 9.77e-4 measured).

#define T_STEPS 2048
#define HID 64
#define NCLS 10
#define XCH 128   // x chunk length (steps)
#define ROWS 4    // batch rows per block

#define KQS 40    // kq stride in shorts (80B = 20 banks, 16B-aligned)
#define KTS 168   // kt stride in shorts (4*KQS + 8 pad; 336B, 16B-aligned)

typedef short bf16x8 __attribute__((ext_vector_type(8)));
typedef float f32x4 __attribute__((ext_vector_type(4)));

__device__ __forceinline__ unsigned short f2bf(float f) {  // RNE f32->bf16
    unsigned u = __builtin_bit_cast(unsigned, f);
    u = u + 0x7FFFu + ((u >> 16) & 1u);
    return (unsigned short)(u >> 16);
}

__global__ __attribute__((amdgpu_flat_work_group_size(256, 256),
                          amdgpu_waves_per_eu(1, 1)))
void lstm_mfma_kernel(
    const float* __restrict__ x,      // [B, 1, T]
    const float* __restrict__ W_ih,   // [256, 1]
    const float* __restrict__ W_hh,   // [256, 64]
    const float* __restrict__ b_ih,   // [256]
    const float* __restrict__ b_hh,   // [256]
    const float* __restrict__ fc1_w,  // [64, 64]
    const float* __restrict__ fc1_b,  // [64]
    const float* __restrict__ fc2_w,  // [10, 64]
    const float* __restrict__ fc2_b,  // [10]
    float* __restrict__ out)          // [B, 10]
{
    const int tid  = threadIdx.x;
    const int lane = tid & 63;
    const int w    = tid >> 6;        // wave id = unit-chunk owner
    const int quad = lane >> 4;       // = batch row within block (D-row 4*quad)
    const int col  = lane & 15;
    const int row0 = blockIdx.x * ROWS;

    const float L2E = 1.4426950408889634f;

    // ---- LDS union: 32KB staging (dead after B-frag load) overlaps runtime ----
    __shared__ __align__(16) char smem[32768];
    short* whi = (short*)smem;                 // staging [0,32768)
    // runtime (valid only after the staging->register handoff sync):
    short (*abuf)[2 * KTS]     = (short(*)[2 * KTS])smem;           // 1344 B
    float (*xlds)[XCH + 4]     = (float(*)[XCH + 4])(smem + 1344);  // 2112 B
    float (*hf)[HID + 1]       = (float(*)[HID + 1])(smem + 3456);  // 1040 B
    float (*r1buf)[HID + 1]    = (float(*)[HID + 1])(smem + 4496);  // 1040 B

    // ---- stage: W_hh f32 -> bf16 fragments, pre-scaled per gate ----
    // tile t_ = g*4 + u4  => wave w (reading t_ = gg*4 + w) gets all 4 gates
    // for units 16w..16w+15.
    for (int idx = tid; idx < 256 * 64; idx += 256) {
        int r_ = idx >> 6;            // gate-major row 0..255
        int k  = idx & 63;
        int g = r_ >> 6, u = r_ & 63;
        float scg = (g == 2) ? -2.0f * L2E : -L2E;
        float f = W_hh[r_ * 64 + k] * scg;
        int u4 = u >> 4, n = u & 15;
        int kt = k >> 5, kq = (k & 31) >> 3, j = k & 7;
        int off = (((g * 4 + u4) * 2 + kt) * 64 + (kq * 16 + n)) * 8 + j;
        whi[off] = (short)f2bf(f);
    }
    __syncthreads();

    // ---- B fragments -> registers (wave w: tiles t_ = gg*4 + w) ----
    const int u0 = w * 16 + col;      // this lane's unit (cols of all 4 tiles)
    bf16x8 Bq[4][2];
    f32x4 biasC[4];
    f32x4 zerov = {0.f, 0.f, 0.f, 0.f};
    #pragma unroll
    for (int gg = 0; gg < 4; ++gg) {
        int t_ = gg * 4 + w;
        #pragma unroll
        for (int kt = 0; kt < 2; ++kt) {
            int off = ((t_ * 2 + kt) * 64 + lane) * 8;
            Bq[gg][kt] = *(const bf16x8*)&whi[off];
            asm volatile("" : "+v"(Bq[gg][kt]));
        }
        float scg = (gg == 2) ? -2.0f * L2E : -L2E;
        float bs = (b_ih[gg * HID + u0] + b_hh[gg * HID + u0]) * scg;
        #pragma unroll
        for (int r = 0; r < 4; ++r) biasC[gg][r] = bs;
    }
    __syncthreads();   // all waves done READING staging; smem may be reused now

    // zero BOTH A buffers (h0 = 0)
    for (int idx = tid; idx < 2 * 2 * KTS; idx += 256) ((short*)abuf)[idx] = 0;

    // ---- update constants: quad q owns cell (batch row q, unit u0) ----
    float wih_u[4];
    #pragma unroll
    for (int gg = 0; gg < 4; ++gg) {
        float scg = (gg == 2) ? -2.0f * L2E : -L2E;
        wih_u[gg] = W_ih[gg * HID + u0] * scg;
    }
    float cc = 0.f, hl = 0.f;

    // invariant LDS coords (compact layout)
    // read: lane l -> kq = l>>4, row' = (l>>2)&3 (valid for A-rows 4*row';
    //        other lanes alias -> garbage D rows, never read)
    const int ard0 = (lane >> 4) * KQS + ((lane >> 2) & 3) * 8;   // kt1 at +KTS
    // write: h(batch quad, unit u0) at (kt=u0>>5, kq=(u0>>3)&3, q=quad, j=u0&7)
    const int awr  = (u0 >> 5) * KTS + ((u0 >> 3) & 3) * KQS + quad * 8 + (u0 & 7);

    const float* xbase = x + (size_t)row0 * T_STEPS;

    // prime x prefetch for chunk 0 (loads issue here, consumed at tc=0)
    float pf0, pf1;
    {
        const float* src = xbase + (size_t)w * T_STEPS;
        pf0 = src[lane];
        pf1 = src[lane + 64];
    }
    __syncthreads();   // abuf zeroed

    auto step = [&](auto cur_c, float xv) __attribute__((always_inline)) {
        constexpr int CUR = decltype(cur_c)::value;
        constexpr int NXT = CUR ^ 1;

        // ---- all 4 gates for units 16w..16w+15, rows {0,4,8,12} ----
        bf16x8 A0 = *(const bf16x8*)&abuf[CUR][ard0];
        bf16x8 A1 = *(const bf16x8*)&abuf[CUR][ard0 + KTS];

        // kt-parallel: two independent MFMAs, combine reg0 with one add
        // (R16 source order: all lo, then all hi; gate order i,f,g,o)
        f32x4 alo[4], ahi[4];
        #pragma unroll
        for (int gg = 0; gg < 4; ++gg)
            alo[gg] = __builtin_amdgcn_mfma_f32_16x16x32_bf16(A0, Bq[gg][0], biasC[gg], 0, 0, 0);
        #pragma unroll
        for (int gg = 0; gg < 4; ++gg)
            ahi[gg] = __builtin_amdgcn_mfma_f32_16x16x32_bf16(A1, Bq[gg][1], zerov, 0, 0, 0);

        // ---- fused update: quad q -> D-row 4q (reg0), ALL 64 lanes active ----
        {
            // pre-scaled args: sigm gates hold -log2e*a, tanh gate -2log2e*a
            float a0 = fmaf(xv, wih_u[0], alo[0][0] + ahi[0][0]);
            float a1 = fmaf(xv, wih_u[1], alo[1][0] + ahi[1][0]);
            float a2 = fmaf(xv, wih_u[2], alo[2][0] + ahi[2][0]);
            float a3 = fmaf(xv, wih_u[3], alo[3][0] + ahi[3][0]);
            float ig = __builtin_amdgcn_rcpf(1.0f + __builtin_amdgcn_exp2f(a0));
            float fg = __builtin_amdgcn_rcpf(1.0f + __builtin_amdgcn_exp2f(a1));
            float gv = fmaf(2.0f, __builtin_amdgcn_rcpf(1.0f + __builtin_amdgcn_exp2f(a2)), -1.0f);
            float og = __builtin_amdgcn_rcpf(1.0f + __builtin_amdgcn_exp2f(a3));
            cc = fmaf(fg, cc, ig * gv);
            float ec = __builtin_amdgcn_exp2f(-2.8853900817779268f * cc);
            float th = fmaf(2.0f, __builtin_amdgcn_rcpf(1.0f + ec), -1.0f);
            hl = og * th;
            unsigned hp;
            asm("v_cvt_pk_bf16_f32 %0, %1, %2" : "=v"(hp) : "v"(hl), "v"(hl));
            abuf[NXT][awr] = (short)hp;
        }
        __syncthreads();   // new h-frags visible (single barrier per step)
    };

    #pragma unroll 1
    for (int tc = 0; tc < T_STEPS; tc += 2) {
        const int tl = tc & (XCH - 1);
        if (tl == 0) {
            // boundary: commit prefetched chunk to LDS, then issue next loads
            xlds[w][lane]      = pf0;
            xlds[w][lane + 64] = pf1;
            __syncthreads();
            int nc = (tc + XCH < T_STEPS) ? (tc + XCH) : tc;  // clamp; tail unused
            const float* src = xbase + (size_t)w * T_STEPS + nc;
            pf0 = src[lane];
            pf1 = src[lane + 64];
        }
        // hoist both steps' x reads (issue with/before A-reads; consumed late)
        float xv0 = xlds[quad][tl];
        float xv1 = xlds[quad][tl + 1];
        step(std::integral_constant<int, 0>{}, xv0);  // reads abuf[0], writes abuf[1]
        step(std::integral_constant<int, 1>{}, xv1);  // reads abuf[1], writes abuf[0]
    }

    // ---- epilogue: gather h, fc1 (relu) + fc2 ----
    hf[quad][u0] = hl;   // (row quad, unit 16w+col): 4x64 values, all lanes
    __syncthreads();

    if (w < ROWS) {
        // thread -> (row = w, unit = lane)
        float s = fc1_b[lane];
        const float4* wrow = (const float4*)(fc1_w + lane * HID);
        #pragma unroll
        for (int j4 = 0; j4 < HID / 4; ++j4) {
            float4 wv = wrow[j4];
            s = fmaf(hf[w][j4 * 4 + 0], wv.x, s);
            s = fmaf(hf[w][j4 * 4 + 1], wv.y, s);
            s = fmaf(hf[w][j4 * 4 + 2], wv.z, s);
            s = fmaf(hf[w][j4 * 4 + 3], wv.w, s);
        }
        r1buf[w][lane] = fmaxf(s, 0.0f);
    }
    __syncthreads();

    if (tid < ROWS * NCLS) {
        int m = tid / NCLS, cls = tid % NCLS;
        float s = fc2_b[cls];
        const float* w2 = fc2_w + cls * HID;
        #pragma unroll
        for (int j = 0; j < HID; ++j) s = fmaf(r1buf[m][j], w2[j], s);
        out[(size_t)(row0 + m) * NCLS + cls] = s;
    }
}

extern "C" void kernel_launch(void* const* d_in, const int* in_sizes, int n_in,
                              void* d_out, int out_size, void* d_ws, size_t ws_size,
                              hipStream_t stream) {
    const float* x     = (const float*)d_in[0];
    const float* W_ih  = (const float*)d_in[1];
    const float* W_hh  = (const float*)d_in[2];
    const float* b_ih  = (const float*)d_in[3];
    const float* b_hh  = (const float*)d_in[4];
    const float* fc1_w = (const float*)d_in[5];
    const float* fc1_b = (const float*)d_in[6];
    const float* fc2_w = (const float*)d_in[7];
    const float* fc2_b = (const float*)d_in[8];
    float* out = (float*)d_out;

    dim3 grid(256);   // 1024 rows / 4 rows per block -> 1 block per CU
    dim3 block(256);  // 4 waves (1 per SIMD)
    lstm_mfma_kernel<<<grid, block, 0, stream>>>(x, W_ih, W_hh, b_ih, b_hh,
                                                 fc1_w, fc1_b, fc2_w, fc2_b, out);
}